// Round 1
// baseline (564.126 us; speedup 1.0000x reference)
//
#include <hip/hip_runtime.h>
#include <math.h>

// Problem constants (from reference setup_inputs)
#define B_  16
#define C_  64
#define HW_ 128
#define E_  8
#define GH_ 16
// per-sample combined weight size: C*C*3*3
#define WSZ 36864   // 64*64*9
// conv tiling
#define TILE 32     // spatial tile (32x32)
#define COT  16     // output channels per block
#define CIC  8      // input-channel chunk staged in LDS
#define HALO 34     // TILE+2
#define XROW 34

// ---------------------------------------------------------------------------
// K1: global average pool. One block per (b,c); 256 threads reduce 16384 vals.
// ---------------------------------------------------------------------------
__global__ __launch_bounds__(256) void pool_kernel(const float* __restrict__ x,
                                                   float* __restrict__ pooled) {
  const int bc = blockIdx.x;  // b*C + c
  const float4* p4 = (const float4*)(x + (size_t)bc * (HW_ * HW_));
  float s = 0.f;
  for (int i = threadIdx.x; i < (HW_ * HW_) / 4; i += 256) {
    float4 v = p4[i];
    s += (v.x + v.y) + (v.z + v.w);
  }
#pragma unroll
  for (int off = 32; off > 0; off >>= 1) s += __shfl_down(s, off, 64);
  __shared__ float red[4];
  if ((threadIdx.x & 63) == 0) red[threadIdx.x >> 6] = s;
  __syncthreads();
  if (threadIdx.x == 0)
    pooled[bc] = (red[0] + red[1] + red[2] + red[3]) * (1.0f / (HW_ * HW_));
}

// ---------------------------------------------------------------------------
// K2: gate MLP + softmax + top-2 + renormalize; also combined bias.
// Single block of 64 threads; threads 0..15 each own one batch sample.
// ---------------------------------------------------------------------------
__global__ __launch_bounds__(64) void gate_kernel(
    const float* __restrict__ pooled, const float* __restrict__ wg1,
    const float* __restrict__ bg1, const float* __restrict__ wg2,
    const float* __restrict__ bg2, const float* __restrict__ b_exp,
    float* __restrict__ probs, float* __restrict__ bcomb) {
  __shared__ float sprobs[B_][E_];
  const int t = threadIdx.x;
  if (t < B_) {
    const int b = t;
    float h[GH_];
#pragma unroll
    for (int g = 0; g < GH_; g++) {
      float s = bg1[g];
      for (int c = 0; c < C_; c++) s = fmaf(pooled[b * C_ + c], wg1[c * GH_ + g], s);
      h[g] = fmaxf(s, 0.f);
    }
    float p[E_];
    float mx = -1e30f;
#pragma unroll
    for (int e = 0; e < E_; e++) {
      float s = bg2[e];
      for (int g = 0; g < GH_; g++) s = fmaf(h[g], wg2[g * E_ + e], s);
      p[e] = s;  // TAU == 1.0
      mx = fmaxf(mx, s);
    }
    float sum = 0.f;
#pragma unroll
    for (int e = 0; e < E_; e++) { p[e] = expf(p[e] - mx); sum += p[e]; }
    float inv = 1.0f / sum;
#pragma unroll
    for (int e = 0; e < E_; e++) p[e] *= inv;
    // top-2 (strict > keeps lowest index on ties, matching lax.top_k)
    int i1 = 0;
#pragma unroll
    for (int e = 1; e < E_; e++) if (p[e] > p[i1]) i1 = e;
    int i2 = -1;
#pragma unroll
    for (int e = 0; e < E_; e++) {
      if (e == i1) continue;
      if (i2 < 0 || p[e] > p[i2]) i2 = e;
    }
    const float denom = p[i1] + p[i2] + 1e-8f;
#pragma unroll
    for (int e = 0; e < E_; e++) {
      float q = (e == i1 || e == i2) ? (p[e] / denom) : 0.f;
      sprobs[b][e] = q;
      probs[b * E_ + e] = q;
    }
  }
  __syncthreads();
  // combined bias: bcomb[b, co] = sum_e sprobs[b][e] * b_exp[e, co]
  for (int i = t; i < B_ * C_; i += 64) {
    const int b = i >> 6;
    const int co = i & 63;
    float s = 0.f;
#pragma unroll
    for (int e = 0; e < E_; e++) s = fmaf(sprobs[b][e], b_exp[e * C_ + co], s);
    bcomb[i] = s;
  }
}

// ---------------------------------------------------------------------------
// K3: combined weights: wcomb[b, co, ci, kh, kw] = sum_e probs[b,e]*w_exp[e,...]
// grid = 16 samples * 144 blocks, 256 threads; fully coalesced over w_exp.
// ---------------------------------------------------------------------------
__global__ __launch_bounds__(256) void combine_kernel(
    const float* __restrict__ w_exp, const float* __restrict__ probs,
    float* __restrict__ wcomb) {
  const int blk = blockIdx.x;             // 0..2303
  const int b = blk / 144;                // 144*256 = 36864 = WSZ
  const int r = (blk - b * 144) * 256 + threadIdx.x;
  float s = 0.f;
#pragma unroll
  for (int e = 0; e < E_; e++)
    s = fmaf(probs[b * E_ + e], w_exp[(size_t)e * WSZ + r], s);
  wcomb[(size_t)b * WSZ + r] = s;
}

// ---------------------------------------------------------------------------
// K4: per-sample 3x3 SAME conv with combined weights + bias + residual.
// grid = (16 spatial tiles, 4 co-tiles, 16 samples), 256 threads.
// Each thread: 4 pixels (rows py0+8r) x 16 output channels.
// ---------------------------------------------------------------------------
__global__ __launch_bounds__(256) void conv_kernel(
    const float* __restrict__ x, const float* __restrict__ wcomb,
    const float* __restrict__ bcomb, float* __restrict__ out) {
  __shared__ float xs[CIC * HALO * XROW];   // 8*34*34 floats = 37 KB
  __shared__ float wsm[COT * CIC * 9];      // 1152 floats

  const int t = threadIdx.x;
  const int tile = blockIdx.x;              // 0..15
  const int cobase = blockIdx.y * COT;      // 0,16,32,48
  const int b = blockIdx.z;                 // 0..15
  const int tx = (tile & 3) * TILE;
  const int ty = (tile >> 2) * TILE;
  const int px = t & 31;                    // 0..31
  const int py0 = t >> 5;                   // 0..7

  float acc[COT][4];
#pragma unroll
  for (int co = 0; co < COT; co++)
#pragma unroll
    for (int r = 0; r < 4; r++) acc[co][r] = 0.f;

  for (int ci0 = 0; ci0 < C_; ci0 += CIC) {
    __syncthreads();
    // stage x halo chunk: CIC channels of 34x34 (zero-padded at borders)
    for (int i = t; i < CIC * HALO * XROW; i += 256) {
      const int ci = i / (HALO * XROW);
      const int rem = i - ci * (HALO * XROW);
      const int hh = rem / XROW;
      const int ww = rem - hh * XROW;
      const int gh = ty + hh - 1;
      const int gw = tx + ww - 1;
      float v = 0.f;
      if (((unsigned)gh < (unsigned)HW_) && ((unsigned)gw < (unsigned)HW_))
        v = x[(((size_t)b * C_ + (ci0 + ci)) * HW_ + gh) * HW_ + gw];
      xs[i] = v;
    }
    // stage weights: wsm[co][ci][k]
    for (int i = t; i < COT * CIC * 9; i += 256) {
      const int co = i / (CIC * 9);
      const int rem = i - co * (CIC * 9);
      wsm[i] = wcomb[(size_t)b * WSZ + (size_t)(cobase + co) * (C_ * 9) +
                     (size_t)ci0 * 9 + rem];
    }
    __syncthreads();

    for (int ci = 0; ci < CIC; ci++) {
#pragma unroll
      for (int kh = 0; kh < 3; kh++) {
#pragma unroll
        for (int kw = 0; kw < 3; kw++) {
          float wv[COT];
#pragma unroll
          for (int co = 0; co < COT; co++)
            wv[co] = wsm[(co * CIC + ci) * 9 + kh * 3 + kw];  // broadcast
#pragma unroll
          for (int r = 0; r < 4; r++) {
            const float xv =
                xs[ci * (HALO * XROW) + (py0 + 8 * r + kh) * XROW + (px + kw)];
#pragma unroll
            for (int co = 0; co < COT; co++)
              acc[co][r] = fmaf(wv[co], xv, acc[co][r]);
          }
        }
      }
    }
  }

  // epilogue: + combined bias + residual x
#pragma unroll
  for (int co = 0; co < COT; co++) {
    const float bias = bcomb[b * C_ + cobase + co];
#pragma unroll
    for (int r = 0; r < 4; r++) {
      const int h = ty + py0 + 8 * r;
      const int w = tx + px;
      const size_t idx = (((size_t)b * C_ + (cobase + co)) * HW_ + h) * HW_ + w;
      out[idx] = acc[co][r] + bias + x[idx];
    }
  }
}

// ---------------------------------------------------------------------------
extern "C" void kernel_launch(void* const* d_in, const int* in_sizes, int n_in,
                              void* d_out, int out_size, void* d_ws,
                              size_t ws_size, hipStream_t stream) {
  const float* x     = (const float*)d_in[0];  // [16,64,128,128]
  const float* wg1   = (const float*)d_in[1];  // [64,16]
  const float* bg1   = (const float*)d_in[2];  // [16]
  const float* wg2   = (const float*)d_in[3];  // [16,8]
  const float* bg2   = (const float*)d_in[4];  // [8]
  const float* w_exp = (const float*)d_in[5];  // [8,64,64,3,3]
  const float* b_exp = (const float*)d_in[6];  // [8,64]
  float* out = (float*)d_out;

  float* ws = (float*)d_ws;
  float* pooled = ws;              // 1024 floats
  float* probs  = ws + 1024;       // 128
  float* bcomb  = ws + 1152;       // 1024
  float* wcomb  = ws + 2176;       // 589824 (16*36864) -> ~2.37 MB total

  pool_kernel<<<B_ * C_, 256, 0, stream>>>(x, pooled);
  gate_kernel<<<1, 64, 0, stream>>>(pooled, wg1, bg1, wg2, bg2, b_exp, probs,
                                    bcomb);
  combine_kernel<<<B_ * (WSZ / 256), 256, 0, stream>>>(w_exp, probs, wcomb);
  conv_kernel<<<dim3(16, 4, B_), 256, 0, stream>>>(x, wcomb, bcomb, out);
}

// Round 2
// 216.666 us; speedup vs baseline: 2.6037x; 2.6037x over previous
//
#include <hip/hip_runtime.h>
#include <hip/hip_bf16.h>
#include <math.h>

#define B_  16
#define C_  64
#define HW_ 128
#define E_  8
#define GH_ 16

typedef __attribute__((ext_vector_type(8))) short short8;
typedef __attribute__((ext_vector_type(4))) float float4v;
typedef __attribute__((ext_vector_type(4))) unsigned int uint4v;

// conv tiling: 32 wide x 8 high spatial tile, 4 waves, wave = 4 Mtiles x 4 Ntiles
#define TW 32
#define TH 8
#define HALO_W 34
#define HALO_H 10
// xs: [10][34][8 groups of 8ci] bf16, group XOR-swizzled by (col&7)
#define XS_ELEMS (HALO_H * HALO_W * 64)   // 21760 bf16 = 43520 B
// per-sample packed weights: [9 pos][2 khalf][4 quad][64 co][8 ci] bf16
#define WB_PER_B (9 * 2 * 4 * 64 * 8)     // 36864

// ---------------------------------------------------------------------------
// K1: convert x fp32 [b][c][h][w] -> bf16 channel-last [b][h][w][c], fused GAP.
// block = (b, h, w-half). LDS transpose 64c x 64w.
// ---------------------------------------------------------------------------
__global__ __launch_bounds__(256) void cvt_pool_kernel(
    const float* __restrict__ x, __hip_bfloat16* __restrict__ xbf,
    float* __restrict__ pooled) {
  __shared__ float tile[64][65];
  const int t = threadIdx.x;
  const int bid = blockIdx.x;
  const int wq = bid & 1;
  const int h = (bid >> 1) & 127;
  const int b = bid >> 8;
  const float* base = x + (size_t)b * (C_ * HW_ * HW_) + (size_t)h * HW_ + wq * 64;
  for (int i = t; i < 4096; i += 256) {
    const int c = i >> 6, w = i & 63;
    tile[c][w] = base[(size_t)c * (HW_ * HW_) + w];
  }
  __syncthreads();
  __hip_bfloat16* ob = xbf + (((size_t)b * HW_ + h) * HW_ + wq * 64) * C_;
  for (int i = t; i < 4096; i += 256) {
    const int w = i >> 6, c = i & 63;
    ob[(size_t)w * C_ + c] = __float2bfloat16(tile[c][w]);
  }
  if (t < 64) {
    float s = 0.f;
    for (int w = 0; w < 64; w++) s += tile[t][w];
    atomicAdd(&pooled[b * C_ + t], s * (1.0f / (HW_ * HW_)));
  }
}

// ---------------------------------------------------------------------------
// K2: gate MLP + softmax + top-2 + renorm + combined bias. 1 block, 64 thr.
// ---------------------------------------------------------------------------
__global__ __launch_bounds__(64) void gate_kernel(
    const float* __restrict__ pooled, const float* __restrict__ wg1,
    const float* __restrict__ bg1, const float* __restrict__ wg2,
    const float* __restrict__ bg2, const float* __restrict__ b_exp,
    float* __restrict__ probs, float* __restrict__ bcomb) {
  __shared__ float sprobs[B_][E_];
  const int t = threadIdx.x;
  if (t < B_) {
    const int b = t;
    float h[GH_];
#pragma unroll
    for (int g = 0; g < GH_; g++) {
      float s = bg1[g];
      for (int c = 0; c < C_; c++) s = fmaf(pooled[b * C_ + c], wg1[c * GH_ + g], s);
      h[g] = fmaxf(s, 0.f);
    }
    float p[E_];
    float mx = -1e30f;
#pragma unroll
    for (int e = 0; e < E_; e++) {
      float s = bg2[e];
      for (int g = 0; g < GH_; g++) s = fmaf(h[g], wg2[g * E_ + e], s);
      p[e] = s;
      mx = fmaxf(mx, s);
    }
    float sum = 0.f;
#pragma unroll
    for (int e = 0; e < E_; e++) { p[e] = expf(p[e] - mx); sum += p[e]; }
    const float inv = 1.0f / sum;
#pragma unroll
    for (int e = 0; e < E_; e++) p[e] *= inv;
    int i1 = 0;
#pragma unroll
    for (int e = 1; e < E_; e++) if (p[e] > p[i1]) i1 = e;
    int i2 = -1;
#pragma unroll
    for (int e = 0; e < E_; e++) {
      if (e == i1) continue;
      if (i2 < 0 || p[e] > p[i2]) i2 = e;
    }
    const float denom = p[i1] + p[i2] + 1e-8f;
#pragma unroll
    for (int e = 0; e < E_; e++) {
      const float q = (e == i1 || e == i2) ? (p[e] / denom) : 0.f;
      sprobs[b][e] = q;
      probs[b * E_ + e] = q;
    }
  }
  __syncthreads();
  for (int i = t; i < B_ * C_; i += 64) {
    const int b = i >> 6, co = i & 63;
    float s = 0.f;
#pragma unroll
    for (int e = 0; e < E_; e++) s = fmaf(sprobs[b][e], b_exp[e * C_ + co], s);
    bcomb[i] = s;
  }
}

// ---------------------------------------------------------------------------
// K3: combined weights, bf16, packed in B-fragment order:
// wB[b][pos][khalf][quad][co][j] = sum_e probs[b,e]*w_exp[e,co,ci,kh,kw]
// where ci = khalf*32 + quad*8 + j, pos = kh*3+kw.
// ---------------------------------------------------------------------------
__global__ __launch_bounds__(256) void combine_kernel(
    const float* __restrict__ w_exp, const float* __restrict__ probs,
    __hip_bfloat16* __restrict__ wB) {
  const int gid = blockIdx.x * 256 + threadIdx.x;  // < 16*36864
  const int j = gid & 7;
  const int co = (gid >> 3) & 63;
  const int quad = (gid >> 9) & 3;
  const int khalf = (gid >> 11) & 1;
  const int pos = (gid >> 12) % 9;
  const int b = gid / WB_PER_B;
  const int ci = khalf * 32 + quad * 8 + j;
  float s = 0.f;
#pragma unroll
  for (int e = 0; e < E_; e++)
    s = fmaf(probs[b * E_ + e],
             w_exp[((size_t)(e * C_ + co) * C_ + ci) * 9 + pos], s);
  wB[gid] = __float2bfloat16(s);
}

// ---------------------------------------------------------------------------
// K4: implicit-GEMM conv via mfma_f32_16x16x32_bf16 + bias + residual.
// grid = (64 tiles, 16 samples), 256 threads (4 waves).
// ---------------------------------------------------------------------------
__global__ __launch_bounds__(256, 2) void conv_kernel(
    const __hip_bfloat16* __restrict__ xbf, const __hip_bfloat16* __restrict__ wB,
    const float* __restrict__ bcomb, const float* __restrict__ x,
    float* __restrict__ out) {
  __shared__ __align__(16) char smem[XS_ELEMS * 2];  // 43520 B
  short* xs = (short*)smem;
  float* lout = (float*)smem;  // epilogue alias: 32 x 260 floats = 33280 B

  const int t = threadIdx.x;
  const int tile = blockIdx.x;
  const int b = blockIdx.y;
  const int tx = (tile & 3) * TW;
  const int ty = (tile >> 2) * TH;
  const int wave = t >> 6;
  const int L = t & 63;
  const int n16 = L & 15;
  const int quad = L >> 4;

  // ---- stage x halo (10x34 pixels x 64 ci), XOR-swizzled 16B groups ----
  for (int i = t; i < HALO_H * HALO_W * 8; i += 256) {  // 2720 chunks of 8 bf16
    const int px = i >> 3;
    const int g = i & 7;
    const int r = px / HALO_W;
    const int c = px - r * HALO_W;
    const int gh = ty + r - 1;
    const int gw = tx + c - 1;
    uint4v v = {0u, 0u, 0u, 0u};
    if (((unsigned)gh < (unsigned)HW_) && ((unsigned)gw < (unsigned)HW_))
      v = *(const uint4v*)(xbf + (((size_t)b * HW_ + gh) * HW_ + gw) * C_ + g * 8);
    *(uint4v*)&xs[(size_t)(px * 8 + (g ^ (c & 7))) * 8] = v;
  }
  __syncthreads();

  float4v acc[4][4];
#pragma unroll
  for (int mt = 0; mt < 4; mt++)
#pragma unroll
    for (int nt = 0; nt < 4; nt++) acc[mt][nt] = (float4v)0.f;

  const __hip_bfloat16* wBp = wB + (size_t)b * WB_PER_B;

#pragma unroll
  for (int pos = 0; pos < 9; pos++) {
    const int kh = pos / 3;
    const int kw = pos - kh * 3;
#pragma unroll
    for (int khalf = 0; khalf < 2; khalf++) {
      // B fragments for all 4 N-tiles (global, L2-hot)
      short8 bf[4];
#pragma unroll
      for (int nt = 0; nt < 4; nt++)
        bf[nt] = *(const short8*)(wBp +
                 (size_t)(((pos * 2 + khalf) * 4 + quad) * 512 + (nt * 16 + n16) * 8));
#pragma unroll
      for (int mt = 0; mt < 4; mt++) {
        const int mtg = wave * 4 + mt;        // global M-tile 0..15
        const int pr = mtg >> 1;              // pixel row 0..7
        const int cb = (mtg & 1) * 16;        // col base 0 or 16
        const int hr = pr + kh;               // halo row
        const int hc = cb + n16 + kw;         // halo col
        const int g = (khalf * 4 + quad) ^ (hc & 7);
        const short8 a =
            *(const short8*)&xs[(size_t)(((hr * HALO_W) + hc) * 8 + g) * 8];
#pragma unroll
        for (int nt = 0; nt < 4; nt++)
          acc[mt][nt] =
              __builtin_amdgcn_mfma_f32_16x16x32_bf16(a, bf[nt], acc[mt][nt], 0, 0, 0);
      }
    }
  }

  // ---- epilogue: LDS bounce for coalesced writes, + bias + fp32 residual ----
#pragma unroll
  for (int chalf = 0; chalf < 2; chalf++) {
    __syncthreads();
#pragma unroll
    for (int mt = 0; mt < 4; mt++) {
      const int mtg = wave * 4 + mt;
      const int pr = mtg >> 1;
      const int cb = (mtg & 1) * 16;
#pragma unroll
      for (int ntl = 0; ntl < 2; ntl++) {
        const int nt = chalf * 2 + ntl;
        const int col_local = ntl * 16 + n16;            // co within 32-chunk
        const int pxb = pr * 32 + cb + quad * 4;          // pixel idx, +reg
        *(float4v*)&lout[(size_t)col_local * 260 + pxb] = acc[mt][nt];
      }
    }
    __syncthreads();
    for (int k = 0; k < 32; k++) {
      const int co = chalf * 32 + k;
      const float bias = bcomb[b * C_ + co];
      const int pr = t >> 5;
      const int pw = t & 31;
      const size_t gidx =
          (((size_t)b * C_ + co) * HW_ + (ty + pr)) * HW_ + (tx + pw);
      out[gidx] = lout[(size_t)k * 260 + pr * 32 + pw] + bias + x[gidx];
    }
  }
}

// ---------------------------------------------------------------------------
extern "C" void kernel_launch(void* const* d_in, const int* in_sizes, int n_in,
                              void* d_out, int out_size, void* d_ws,
                              size_t ws_size, hipStream_t stream) {
  const float* x     = (const float*)d_in[0];
  const float* wg1   = (const float*)d_in[1];
  const float* bg1   = (const float*)d_in[2];
  const float* wg2   = (const float*)d_in[3];
  const float* bg2   = (const float*)d_in[4];
  const float* w_exp = (const float*)d_in[5];
  const float* b_exp = (const float*)d_in[6];
  float* out = (float*)d_out;

  float* ws = (float*)d_ws;
  float* pooled = ws;                 // 1024 floats
  float* probs  = ws + 1024;          // 128
  float* bcomb  = ws + 1152;          // 1024
  __hip_bfloat16* xbf = (__hip_bfloat16*)(ws + 4096);           // 16.7M bf16
  __hip_bfloat16* wB  = xbf + (size_t)B_ * HW_ * HW_ * C_;      // 589824 bf16

  hipMemsetAsync(pooled, 0, B_ * C_ * sizeof(float), stream);
  cvt_pool_kernel<<<B_ * HW_ * 2, 256, 0, stream>>>(x, xbf, pooled);
  gate_kernel<<<1, 64, 0, stream>>>(pooled, wg1, bg1, wg2, bg2, b_exp, probs,
                                    bcomb);
  combine_kernel<<<(B_ * WB_PER_B) / 256, 256, 0, stream>>>(w_exp, probs, wB);
  conv_kernel<<<dim3(64, B_), 256, 0, stream>>>(xbf, wB, bcomb, x, out);
}

// Round 3
// 207.707 us; speedup vs baseline: 2.7160x; 1.0431x over previous
//
#include <hip/hip_runtime.h>
#include <hip/hip_bf16.h>
#include <math.h>

#define B_  16
#define C_  64
#define HW_ 128
#define E_  8
#define GH_ 16

typedef __attribute__((ext_vector_type(8))) short short8;
typedef __attribute__((ext_vector_type(4))) float float4v;
typedef __attribute__((ext_vector_type(4))) unsigned int uint4v;

// conv tiling: 32 wide x 8 high spatial tile, 4 waves, wave = 4 Mtiles x 4 Ntiles
#define TW 32
#define TH 8
#define HALO_W 34
#define HALO_H 10
// xs: one 32-ci half: 340 pixels x 32ci bf16, 16B chunks swizzled g^((c>>1)&3)
#define XS_SHORTS (HALO_H * HALO_W * 32)     // 10880 shorts = 21760 B
// epilogue lout: 32 co x (8 rows x 36 pad) floats, co-stride 292
#define LOUT_FLOATS (32 * 292)               // 9344 floats = 37376 B
#define SMEM_BYTES 37376
// per-sample packed weights: [9 pos][2 khalf][4 quad][64 co][8 ci] bf16
#define WB_PER_B (9 * 2 * 4 * 64 * 8)        // 36864

// ---------------------------------------------------------------------------
// K1: x fp32 [b][c][h][w] -> bf16 [b][h][w][c], fused GAP partial sums.
// block = (b, h, w-half); float4 reads, ushort4 stores.
// ---------------------------------------------------------------------------
__global__ __launch_bounds__(256) void cvt_pool_kernel(
    const float* __restrict__ x, __hip_bfloat16* __restrict__ xbf,
    float* __restrict__ pooled) {
  __shared__ float tile[64][68];
  const int t = threadIdx.x;
  const int bid = blockIdx.x;
  const int wq = bid & 1;
  const int h = (bid >> 1) & 127;
  const int b = bid >> 8;
  const float* base = x + (size_t)b * (C_ * HW_ * HW_) + (size_t)h * HW_ + wq * 64;
#pragma unroll
  for (int it = 0; it < 4; it++) {
    const int i = t + it * 256;           // 0..1023
    const int c = i >> 4;
    const int w4 = (i & 15) * 4;
    const float4v v = *(const float4v*)(base + (size_t)c * (HW_ * HW_) + w4);
    *(float4v*)&tile[c][w4] = v;
  }
  __syncthreads();
  if (t < 64) {
    float4v s4 = (float4v)0.f;
#pragma unroll
    for (int w4 = 0; w4 < 16; w4++) {
      const float4v v = *(const float4v*)&tile[t][w4 * 4];
      s4 += v;
    }
    const float s = (s4.x + s4.y) + (s4.z + s4.w);
    atomicAdd(&pooled[b * C_ + t], s * (1.0f / (HW_ * HW_)));
  }
  __hip_bfloat16* ob = xbf + (((size_t)b * HW_ + h) * HW_ + wq * 64) * C_;
#pragma unroll
  for (int it = 0; it < 4; it++) {
    const int i = t + it * 256;
    const int w = i >> 4;
    const int c4 = (i & 15) * 4;
    unsigned short us[4];
#pragma unroll
    for (int k = 0; k < 4; k++) {
      __hip_bfloat16 hb = __float2bfloat16(tile[c4 + k][w]);
      us[k] = *(unsigned short*)&hb;
    }
    *(ushort2*)0;  // (no-op placeholder removed below)
    unsigned long long packed = (unsigned long long)us[0] |
                                ((unsigned long long)us[1] << 16) |
                                ((unsigned long long)us[2] << 32) |
                                ((unsigned long long)us[3] << 48);
    *(unsigned long long*)(ob + (size_t)w * C_ + c4) = packed;
  }
}

// ---------------------------------------------------------------------------
// K2: gate MLP + softmax + top-2 + renorm + combined bias. 1 block, 64 thr.
// ---------------------------------------------------------------------------
__global__ __launch_bounds__(64) void gate_kernel(
    const float* __restrict__ pooled, const float* __restrict__ wg1,
    const float* __restrict__ bg1, const float* __restrict__ wg2,
    const float* __restrict__ bg2, const float* __restrict__ b_exp,
    float* __restrict__ probs, float* __restrict__ bcomb) {
  __shared__ float sprobs[B_][E_];
  const int t = threadIdx.x;
  if (t < B_) {
    const int b = t;
    float h[GH_];
#pragma unroll
    for (int g = 0; g < GH_; g++) {
      float s = bg1[g];
      for (int c = 0; c < C_; c++) s = fmaf(pooled[b * C_ + c], wg1[c * GH_ + g], s);
      h[g] = fmaxf(s, 0.f);
    }
    float p[E_];
    float mx = -1e30f;
#pragma unroll
    for (int e = 0; e < E_; e++) {
      float s = bg2[e];
      for (int g = 0; g < GH_; g++) s = fmaf(h[g], wg2[g * E_ + e], s);
      p[e] = s;
      mx = fmaxf(mx, s);
    }
    float sum = 0.f;
#pragma unroll
    for (int e = 0; e < E_; e++) { p[e] = expf(p[e] - mx); sum += p[e]; }
    const float inv = 1.0f / sum;
#pragma unroll
    for (int e = 0; e < E_; e++) p[e] *= inv;
    int i1 = 0;
#pragma unroll
    for (int e = 1; e < E_; e++) if (p[e] > p[i1]) i1 = e;
    int i2 = -1;
#pragma unroll
    for (int e = 0; e < E_; e++) {
      if (e == i1) continue;
      if (i2 < 0 || p[e] > p[i2]) i2 = e;
    }
    const float denom = p[i1] + p[i2] + 1e-8f;
#pragma unroll
    for (int e = 0; e < E_; e++) {
      const float q = (e == i1 || e == i2) ? (p[e] / denom) : 0.f;
      sprobs[b][e] = q;
      probs[b * E_ + e] = q;
    }
  }
  __syncthreads();
  for (int i = t; i < B_ * C_; i += 64) {
    const int b = i >> 6, co = i & 63;
    float s = 0.f;
#pragma unroll
    for (int e = 0; e < E_; e++) s = fmaf(sprobs[b][e], b_exp[e * C_ + co], s);
    bcomb[i] = s;
  }
}

// ---------------------------------------------------------------------------
// K3: combined weights -> packed B-fragment layout, via coalesced read +
// LDS transpose. block = (b, co-group of 8). grid = 16*8 = 128.
// wB[b][pos][khalf][quad][co][j], ci = khalf*32+quad*8+j.
// ---------------------------------------------------------------------------
__global__ __launch_bounds__(256) void combine_kernel(
    const float* __restrict__ w_exp, const float* __restrict__ probs,
    __hip_bfloat16* __restrict__ wB) {
  __shared__ float wtmp[8 * 576];   // 18.4 KB
  const int t = threadIdx.x;
  const int b = blockIdx.x >> 3;
  const int cog = blockIdx.x & 7;
  float pb[E_];
#pragma unroll
  for (int e = 0; e < E_; e++) pb[e] = probs[b * E_ + e];
  // coalesced combine: 8 co x 576 contiguous floats per expert
  const size_t src0 = (size_t)cog * 8 * 576;
  for (int i = t; i < 4608; i += 256) {
    float s = 0.f;
#pragma unroll
    for (int e = 0; e < E_; e++)
      s = fmaf(pb[e], w_exp[(size_t)e * (C_ * 576) + src0 + i], s);
    wtmp[i] = s;
  }
  __syncthreads();
  // packed write: consecutive i -> consecutive (co_l, j) -> 128B runs
  for (int i = t; i < 4608; i += 256) {
    const int j = i & 7;
    const int co_l = (i >> 3) & 7;
    const int rest = i >> 6;          // 0..71
    const int quad = rest & 3;
    const int khalf = (rest >> 2) & 1;
    const int pos = rest >> 3;
    const int ci = khalf * 32 + quad * 8 + j;
    const float v = wtmp[co_l * 576 + ci * 9 + pos];
    const int co = cog * 8 + co_l;
    wB[(size_t)b * WB_PER_B +
       ((((pos * 2 + khalf) * 4 + quad) * 64) + co) * 8 + j] =
        __float2bfloat16(v);
  }
}

// ---------------------------------------------------------------------------
// K4: implicit-GEMM conv (mfma_f32_16x16x32_bf16), 2-half K-split,
// B-fragment double-buffer prefetch, vectorized epilogue. grid (64,16).
// ---------------------------------------------------------------------------
__global__ __launch_bounds__(256, 4) void conv_kernel(
    const __hip_bfloat16* __restrict__ xbf, const __hip_bfloat16* __restrict__ wB,
    const float* __restrict__ bcomb, const float* __restrict__ x,
    float* __restrict__ out) {
  __shared__ __align__(16) char smem[SMEM_BYTES];
  short* xs = (short*)smem;
  float* lout = (float*)smem;

  const int t = threadIdx.x;
  const int tile = blockIdx.x;
  const int b = blockIdx.y;
  const int tx = (tile & 3) * TW;
  const int ty = (tile >> 2) * TH;
  const int wave = t >> 6;
  const int L = t & 63;
  const int n16 = L & 15;
  const int quad = L >> 4;

  float4v acc[4][4];
#pragma unroll
  for (int mt = 0; mt < 4; mt++)
#pragma unroll
    for (int nt = 0; nt < 4; nt++) acc[mt][nt] = (float4v)0.f;

  for (int half = 0; half < 2; half++) {
    __syncthreads();
    // ---- stage one 32-ci half of the 10x34 halo ----
    for (int i = t; i < HALO_H * HALO_W * 4; i += 256) {  // 1360 chunks of 16B
      const int p = i >> 2;
      const int g = i & 3;
      const int r = p / HALO_W;
      const int c = p - r * HALO_W;
      const int gh = ty + r - 1;
      const int gw = tx + c - 1;
      uint4v v = {0u, 0u, 0u, 0u};
      if (((unsigned)gh < (unsigned)HW_) && ((unsigned)gw < (unsigned)HW_))
        v = *(const uint4v*)(xbf + (((size_t)b * HW_ + gh) * HW_ + gw) * C_ +
                             half * 32 + g * 8);
      const int slot = g ^ ((c >> 1) & 3);
      *(uint4v*)&xs[p * 32 + slot * 8] = v;
    }
    __syncthreads();

    // B fragments: double-buffered prefetch from global (L2-hot)
    const __hip_bfloat16* wBh =
        wB + (size_t)b * WB_PER_B + (size_t)(half * 4 + quad) * 512 + n16 * 8;
    short8 bf[2][4];
#pragma unroll
    for (int nt = 0; nt < 4; nt++)
      bf[0][nt] = *(const short8*)(wBh + nt * 128);

#pragma unroll
    for (int pos = 0; pos < 9; pos++) {
      const int cur = pos & 1;
      if (pos < 8) {
#pragma unroll
        for (int nt = 0; nt < 4; nt++)
          bf[cur ^ 1][nt] =
              *(const short8*)(wBh + (size_t)(pos + 1) * 4096 + nt * 128);
      }
      const int kh = pos / 3;
      const int kw = pos - kh * 3;
      short8 a[4];
#pragma unroll
      for (int mt = 0; mt < 4; mt++) {
        const int mtg = wave * 4 + mt;
        const int pr = mtg >> 1;
        const int cb = (mtg & 1) * 16;
        const int hr = pr + kh;
        const int hc = cb + n16 + kw;
        const int p = hr * HALO_W + hc;
        const int slot = quad ^ ((hc >> 1) & 3);
        a[mt] = *(const short8*)&xs[p * 32 + slot * 8];
      }
#pragma unroll
      for (int mt = 0; mt < 4; mt++)
#pragma unroll
        for (int nt = 0; nt < 4; nt++)
          acc[mt][nt] = __builtin_amdgcn_mfma_f32_16x16x32_bf16(
              a[mt], bf[cur][nt], acc[mt][nt], 0, 0, 0);
    }
  }

  // ---- epilogue: 2 chunks of 32 co; float4 LDS bounce + residual ----
#pragma unroll
  for (int ch = 0; ch < 2; ch++) {
    __syncthreads();
#pragma unroll
    for (int mt = 0; mt < 4; mt++) {
      const int mtg = wave * 4 + mt;
      const int pr = mtg >> 1;
      const int cb = (mtg & 1) * 16;
#pragma unroll
      for (int ntl = 0; ntl < 2; ntl++) {
        const int k = ntl * 16 + n16;
        *(float4v*)&lout[k * 292 + pr * 36 + cb + quad * 4] = acc[mt][ch * 2 + ntl];
      }
    }
    __syncthreads();
#pragma unroll
    for (int it = 0; it < 8; it++) {
      const int idx4 = it * 256 + t;
      const int k = idx4 >> 6;           // co within chunk
      const int rem = idx4 & 63;
      const int pr = rem >> 3;
      const int pw4 = (rem & 7) * 4;
      const int co = ch * 32 + k;
      const float4v v = *(const float4v*)&lout[k * 292 + pr * 36 + pw4];
      const size_t gi =
          (((size_t)b * C_ + co) * HW_ + (ty + pr)) * HW_ + (tx + pw4);
      const float4v xr = *(const float4v*)(x + gi);
      const float bias = bcomb[b * C_ + co];
      float4v o;
      o.x = v.x + xr.x + bias;
      o.y = v.y + xr.y + bias;
      o.z = v.z + xr.z + bias;
      o.w = v.w + xr.w + bias;
      *(float4v*)(out + gi) = o;
    }
  }
}

// ---------------------------------------------------------------------------
extern "C" void kernel_launch(void* const* d_in, const int* in_sizes, int n_in,
                              void* d_out, int out_size, void* d_ws,
                              size_t ws_size, hipStream_t stream) {
  const float* x     = (const float*)d_in[0];
  const float* wg1   = (const float*)d_in[1];
  const float* bg1   = (const float*)d_in[2];
  const float* wg2   = (const float*)d_in[3];
  const float* bg2   = (const float*)d_in[4];
  const float* w_exp = (const float*)d_in[5];
  const float* b_exp = (const float*)d_in[6];
  float* out = (float*)d_out;

  float* ws = (float*)d_ws;
  float* pooled = ws;                 // 1024 floats
  float* probs  = ws + 1024;          // 128
  float* bcomb  = ws + 1152;          // 1024
  __hip_bfloat16* xbf = (__hip_bfloat16*)(ws + 4096);           // 16.7M bf16
  __hip_bfloat16* wB  = xbf + (size_t)B_ * HW_ * HW_ * C_;      // 589824 bf16

  hipMemsetAsync(pooled, 0, B_ * C_ * sizeof(float), stream);
  cvt_pool_kernel<<<B_ * HW_ * 2, 256, 0, stream>>>(x, xbf, pooled);
  gate_kernel<<<1, 64, 0, stream>>>(pooled, wg1, bg1, wg2, bg2, b_exp, probs,
                                    bcomb);
  combine_kernel<<<B_ * 8, 256, 0, stream>>>(w_exp, probs, wB);
  conv_kernel<<<dim3(64, B_), 256, 0, stream>>>(xbf, wB, bcomb, x, out);
}